// Round 5
// baseline (340.948 us; speedup 1.0000x reference)
//
#include <hip/hip_runtime.h>
#include <math.h>

#define N_NODES 50000
#define N_EDGES 800000
#define D 128
#define NBLK 196   // ceil(N_NODES/256)
#define GATHER_BLOCKS 2048

typedef __attribute__((ext_vector_type(8))) short bf16x8;
typedef __attribute__((ext_vector_type(4))) float f32x4;
typedef __attribute__((ext_vector_type(4))) unsigned int u32x4;

static __device__ __forceinline__ unsigned short f2bf(float f) {
    unsigned int u = __float_as_uint(f);
    u = (u + 0x7fffu + ((u >> 16) & 1u)) >> 16;
    return (unsigned short)u;
}
static __device__ __forceinline__ float bf2f(unsigned short h) {
    return __uint_as_float(((unsigned int)h) << 16);
}

// ---------------- fused prep: degree+rank histogram + split x + weight split-casts ----------------
__global__ void prep_deg_kernel(const int* __restrict__ dst, int* __restrict__ deg,
                                int* __restrict__ rank,
                                const float* __restrict__ x,
                                const float* __restrict__ W1l, const float* __restrict__ W1r,
                                const float* __restrict__ W2l, const float* __restrict__ W2r,
                                const float* __restrict__ Wlin,
                                unsigned short* __restrict__ xhi, unsigned short* __restrict__ xlo,
                                unsigned short* __restrict__ W1hi, unsigned short* __restrict__ W1lo,
                                unsigned short* __restrict__ W2hi, unsigned short* __restrict__ W2lo,
                                unsigned short* __restrict__ WLhi, unsigned short* __restrict__ WLlo) {
    int b = blockIdx.x, tid = threadIdx.x;
    if (b < 3125) {
        int e = b * 256 + tid;
        rank[e] = atomicAdd(&deg[dst[e]], 1);   // rank within dst bucket
    } else if (b < 9375) {
        int i = ((b - 3125) * 256 + tid) * 4;
        float4 v = *(const float4*)(x + i);
        ushort4 h, l;
        h.x = f2bf(v.x); l.x = f2bf(v.x - bf2f(h.x));
        h.y = f2bf(v.y); l.y = f2bf(v.y - bf2f(h.y));
        h.z = f2bf(v.z); l.z = f2bf(v.z - bf2f(h.z));
        h.w = f2bf(v.w); l.w = f2bf(v.w - bf2f(h.w));
        *(ushort4*)(xhi + i) = h;
        *(ushort4*)(xlo + i) = l;
    } else if (b < 9503) {
        int isW2 = (b >= 9439);
        const float* A = isW2 ? W2l : W1l;
        const float* B = isW2 ? W2r : W1r;
        unsigned short* hi = isW2 ? W2hi : W1hi;
        unsigned short* lo = isW2 ? W2lo : W1lo;
        int f = (b - (isW2 ? 9439 : 9375)) * 2 + (tid >> 7);
        int t = tid & 127;
        float va = A[f * 128 + t], vb = B[f * 128 + t];
        unsigned short ha = f2bf(va), hb = f2bf(vb);
        hi[f * 256 + t]       = ha;
        hi[f * 256 + 128 + t] = hb;
        lo[f * 256 + t]       = f2bf(va - bf2f(ha));
        lo[f * 256 + 128 + t] = f2bf(vb - bf2f(hb));
    } else {
        int f = b - 9503;
        float v = (f < 40) ? Wlin[f * 256 + tid] : 0.f;
        unsigned short h = f2bf(v);
        WLhi[f * 256 + tid] = h;
        WLlo[f * 256 + tid] = f2bf(v - bf2f(h));
    }
}

// ---------------- 2-stage scan ----------------
__global__ void scan_partial(const int* __restrict__ deg, int* __restrict__ bsum) {
    __shared__ int wt[4];
    int tid = threadIdx.x, lane = tid & 63, wv = tid >> 6;
    int idx = blockIdx.x * 256 + tid;
    int v = (idx < N_NODES) ? deg[idx] : 0;
    int s = v;
    #pragma unroll
    for (int o = 1; o < 64; o <<= 1) s += __shfl_xor(s, o, 64);
    if (lane == 0) wt[wv] = s;
    __syncthreads();
    if (tid == 0) bsum[blockIdx.x] = wt[0] + wt[1] + wt[2] + wt[3];
}

__global__ void scan_write(const int* __restrict__ deg, const int* __restrict__ bsum,
                           int* __restrict__ rowptr) {
    __shared__ int wt[4], wt2[4];
    int tid = threadIdx.x, lane = tid & 63, wv = tid >> 6;
    int v0 = (tid < blockIdx.x) ? bsum[tid] : 0;   // blockIdx.x <= 195 < 256
    int s0 = v0;
    #pragma unroll
    for (int o = 1; o < 64; o <<= 1) s0 += __shfl_xor(s0, o, 64);
    if (lane == 0) wt2[wv] = s0;
    int idx = blockIdx.x * 256 + tid;
    int v = (idx < N_NODES) ? deg[idx] : 0;
    int s = v;
    #pragma unroll
    for (int o = 1; o < 64; o <<= 1) { int t = __shfl_up(s, o, 64); if (lane >= o) s += t; }
    if (lane == 63) wt[wv] = s;
    __syncthreads();
    int boff = wt2[0] + wt2[1] + wt2[2] + wt2[3];
    #pragma unroll
    for (int w = 0; w < 4; w++) boff += (w < wv) ? wt[w] : 0;
    int excl = boff + s - v;
    if (idx < N_NODES) rowptr[idx] = excl;
    if (idx == 0) rowptr[N_NODES] = N_EDGES;
}

// ---------------- bucket edges by dst (atomic-free: pos = rowptr[dst] + rank) ----------------
__global__ void bucket_kernel(const int* __restrict__ src, const int* __restrict__ dst,
                              const int* __restrict__ rowptr, const int* __restrict__ rank,
                              int* __restrict__ srcs_sorted) {
    int e = blockIdx.x * blockDim.x + threadIdx.x;
    if (e < N_EDGES) {
        srcs_sorted[rowptr[dst[e]] + rank[e]] = src[e];
    }
}

// ---------------- gather-mean kernel (split out: no LDS -> 32 waves/CU) ----------------
// 16 lanes cover one 256 B row (dwordx4); 4 rows per wave-instr; 2-node (A/B adjacent,
// so rowptr[nB]=rowptr[nA+1] shares a load and srcs strips are contiguous) x unroll-2
// streams ~ 64 lines in flight per wave. Writes agg mean as hi+lo bf16 planes (coalesced).
__global__ __launch_bounds__(256, 8) void gather_mean(
    const int* __restrict__ srcs, const int* __restrict__ rowptr,
    const unsigned short* __restrict__ Shi,
    unsigned short* __restrict__ Aghi, unsigned short* __restrict__ Aglo)
{
    const int tid = threadIdx.x;
    const int wv = tid >> 6, lane = tid & 63;
    const int g = lane >> 4, q = lane & 15;
    const int qb = q << 4;
    const char* xb = (const char*)Shi;          // row = 256 bytes
    const int wid = blockIdx.x * 4 + wv;
    const int NW = GATHER_BLOCKS * 4;
    #pragma unroll 1
    for (int p = wid; p < N_NODES / 2; p += NW) {
        const int nA = 2 * p, nB = 2 * p + 1;
        const int begA = rowptr[nA];
        const int endA = rowptr[nA + 1];
        const int endB = rowptr[nB + 1];
        const int begB = endA;
        const int degA = endA - begA, degB = endB - begB;
        float ax[4] = {0,0,0,0}, ay[4] = {0,0,0,0};
        float bx[4] = {0,0,0,0}, by[4] = {0,0,0,0};
        int nsA = (degA + 63) >> 6, nsB = (degB + 63) >> 6;
        int nsmax = max(nsA, nsB);
        #pragma unroll 1
        for (int st = 0; st < nsmax; st++) {
            int svA = 0, svB = 0, nbA = 0, nbB = 0;
            if (st < nsA) {                     // wave-uniform branch
                int sb = begA + (st << 6);
                nbA = min(64, endA - sb);
                svA = srcs[min(sb + lane, endA - 1)];   // 64 edge ids, coalesced
            }
            if (st < nsB) {
                int sb = begB + (st << 6);
                nbB = min(64, endB - sb);
                svB = srcs[min(sb + lane, endB - 1)];
            }
            int itA = (nbA + 3) >> 2, itB = (nbB + 3) >> 2;
            int itmax = max(itA, itB);
            #pragma unroll 2
            for (int b = 0; b < itmax; b++) {
                int ei = (b << 2) + g;          // edge slot within strip for this group
                if (b < itA) {                  // wave-uniform
                    unsigned sv = (unsigned)__shfl(svA, ei, 64);
                    u32x4 v = *(const u32x4*)(xb + ((sv << 8) + qb));
                    v.x = (ei < nbA) ? v.x : 0u;
                    v.y = (ei < nbA) ? v.y : 0u;
                    v.z = (ei < nbA) ? v.z : 0u;
                    v.w = (ei < nbA) ? v.w : 0u;
                    ax[0] += __uint_as_float(v.x << 16); ay[0] += __uint_as_float(v.x & 0xffff0000u);
                    ax[1] += __uint_as_float(v.y << 16); ay[1] += __uint_as_float(v.y & 0xffff0000u);
                    ax[2] += __uint_as_float(v.z << 16); ay[2] += __uint_as_float(v.z & 0xffff0000u);
                    ax[3] += __uint_as_float(v.w << 16); ay[3] += __uint_as_float(v.w & 0xffff0000u);
                }
                if (b < itB) {
                    unsigned sv = (unsigned)__shfl(svB, ei, 64);
                    u32x4 v = *(const u32x4*)(xb + ((sv << 8) + qb));
                    v.x = (ei < nbB) ? v.x : 0u;
                    v.y = (ei < nbB) ? v.y : 0u;
                    v.z = (ei < nbB) ? v.z : 0u;
                    v.w = (ei < nbB) ? v.w : 0u;
                    bx[0] += __uint_as_float(v.x << 16); by[0] += __uint_as_float(v.x & 0xffff0000u);
                    bx[1] += __uint_as_float(v.y << 16); by[1] += __uint_as_float(v.y & 0xffff0000u);
                    bx[2] += __uint_as_float(v.z << 16); by[2] += __uint_as_float(v.z & 0xffff0000u);
                    by[3] += 0.f;
                    bx[3] += __uint_as_float(v.w << 16); by[3] += __uint_as_float(v.w & 0xffff0000u);
                }
            }
        }
        // cross-group reduce: lanes {l, l^16, l^32, l^48} hold partials of the same features
        #pragma unroll
        for (int d = 0; d < 4; d++) {
            ax[d] += __shfl_xor(ax[d], 16, 64); ax[d] += __shfl_xor(ax[d], 32, 64);
            ay[d] += __shfl_xor(ay[d], 16, 64); ay[d] += __shfl_xor(ay[d], 32, 64);
            bx[d] += __shfl_xor(bx[d], 16, 64); bx[d] += __shfl_xor(bx[d], 32, 64);
            by[d] += __shfl_xor(by[d], 16, 64); by[d] += __shfl_xor(by[d], 32, 64);
        }
        if (g == 0) {   // 16 lanes write one u32x4 per plane per node (coalesced 256 B)
            float invA = 1.0f / fmaxf((float)degA, 1.0f);
            float invB = 1.0f / fmaxf((float)degB, 1.0f);
            u32x4 ha, la, hb, lb;
            #pragma unroll
            for (int d = 0; d < 4; d++) {
                float sx = ax[d] * invA, sy = ay[d] * invA;
                unsigned short h0 = f2bf(sx), h1 = f2bf(sy);
                unsigned short l0 = f2bf(sx - bf2f(h0)), l1 = f2bf(sy - bf2f(h1));
                ha[d] = (unsigned)h0 | ((unsigned)h1 << 16);
                la[d] = (unsigned)l0 | ((unsigned)l1 << 16);
                float tx = bx[d] * invB, ty = by[d] * invB;
                unsigned short h2 = f2bf(tx), h3 = f2bf(ty);
                unsigned short l2 = f2bf(tx - bf2f(h2)), l3 = f2bf(ty - bf2f(h3));
                hb[d] = (unsigned)h2 | ((unsigned)h3 << 16);
                lb[d] = (unsigned)l2 | ((unsigned)l3 << 16);
            }
            *(u32x4*)(Aghi + (size_t)nA * D + q * 8) = ha;
            *(u32x4*)(Aglo + (size_t)nA * D + q * 8) = la;
            *(u32x4*)(Aghi + (size_t)nB * D + q * 8) = hb;
            *(u32x4*)(Aglo + (size_t)nB * D + q * 8) = lb;
        }
    }
}

// ---------------- GEMM kernel: split-bf16 MFMA, A-frags straight from HBM ----------------
// Block = 512 thr (8 waves) = 64 nodes x 128 outputs. LDS 17.4 KB -> 4 blocks/CU (wave-
// slot-capped), grid 782 <= 1024 capacity -> ONE round. Round-4's FINAL stashed h2 in a
// 34 KB LDS buffer -> 52 KB LDS -> 3 blocks/CU -> 768 capacity < 782 grid -> TWO full
// rounds (76 us). Now h2 goes through a global scratch (Ohi/Olo) that the same block
// reads back in phase 3 (same-CU L1 / same-XCD L2 hits; __syncthreads fences global
// within the block). Whi staged in LDS (round-2 A/B: direct global B-hi cost +19 us).
template<bool FINAL>
__global__ __launch_bounds__(512, 4) void gemm_layer(
    const unsigned short* __restrict__ Aghi, const unsigned short* __restrict__ Aglo,  // agg planes
    const unsigned short* __restrict__ A2hi, const unsigned short* __restrict__ A2lo,  // self planes
    const unsigned short* __restrict__ Whi, const unsigned short* __restrict__ Wlo,    // [128,256]
    const float* __restrict__ bias,
    unsigned short* __restrict__ Ohi, unsigned short* __restrict__ Olo,         // layer out / h2 scratch
    const unsigned short* __restrict__ WLhi, const unsigned short* __restrict__ WLlo,  // [48,256]
    const float* __restrict__ blin, float* __restrict__ out)                    // (if FINAL)
{
    __shared__ unsigned short Wl[8192];                 // 16 KB (Whi quarter stage)
    __shared__ float stats[256];                        // softmax stats (FINAL)

    const int tid = threadIdx.x;
    const int wv = tid >> 6, lane = tid & 63;
    const int nb0 = blockIdx.x * 64;
    const int m = lane & 15, quad = lane >> 4;
    const int gg = wv & 3, tp = wv >> 2;
    const int nodec = min(nb0 + gg * 16 + m, N_NODES - 1);

    // A1 frags (agg, K 0..127) + A2 frags (self, K 128..255) from global, coalesced-ish
    bf16x8 a1h[4], a1l[4], a2h[4], a2l[4];
    {
        const unsigned short* r1h = Aghi + (size_t)nodec * D + quad * 8;
        const unsigned short* r1l = Aglo + (size_t)nodec * D + quad * 8;
        const unsigned short* r2h = A2hi + (size_t)nodec * D + quad * 8;
        const unsigned short* r2l = A2lo + (size_t)nodec * D + quad * 8;
        #pragma unroll
        for (int ks = 0; ks < 4; ks++) {
            a1h[ks] = *(const bf16x8*)(r1h + ks * 32);
            a1l[ks] = *(const bf16x8*)(r1l + ks * 32);
            a2h[ks] = *(const bf16x8*)(r2h + ks * 32);
            a2l[ks] = *(const bf16x8*)(r2l + ks * 32);
        }
    }

    // ---- GEMM over 4 f-quarters (Whi staged 16 KB at a time) ----
    #pragma unroll 1
    for (int fq = 0; fq < 4; fq++) {
        const int f0 = fq * 32;
        if (fq) __syncthreads();
        #pragma unroll
        for (int itS = 0; itS < 2; itS++) {
            int c = tid + itS * 512;                 // 1024 chunks of 16B
            int nt = c >> 9, w2 = c & 511;
            int ks = w2 >> 6, lidx = w2 & 63;
            int mm = lidx >> 2, qq = lidx & 3;
            const unsigned short* gp = Whi + (size_t)(f0 + nt * 16 + mm) * 256 + ks * 32 + qq * 8;
            *(bf16x8*)&Wl[(size_t)c * 8] = *(const bf16x8*)gp;
        }
        __syncthreads();

        int f = f0 + tp * 16 + m;
        const unsigned short* wlorow = Wlo + (size_t)f * 256 + quad * 8;
        f32x4 acc0 = {0.f, 0.f, 0.f, 0.f};
        f32x4 acc1 = {0.f, 0.f, 0.f, 0.f};
        f32x4 acc2 = {0.f, 0.f, 0.f, 0.f};
        #pragma unroll
        for (int ks = 0; ks < 8; ks++) {
            bf16x8 bh = *(const bf16x8*)&Wl[(size_t)(((tp * 8 + ks) << 6) + (m * 4 + quad)) * 8];
            bf16x8 bl = *(const bf16x8*)(wlorow + ks * 32);
            bf16x8 ah = (ks < 4) ? a1h[ks] : a2h[ks - 4];
            bf16x8 al = (ks < 4) ? a1l[ks] : a2l[ks - 4];
            acc0 = __builtin_amdgcn_mfma_f32_16x16x32_bf16(ah, bh, acc0, 0, 0, 0);
            acc1 = __builtin_amdgcn_mfma_f32_16x16x32_bf16(ah, bl, acc1, 0, 0, 0);
            acc2 = __builtin_amdgcn_mfma_f32_16x16x32_bf16(al, bh, acc2, 0, 0, 0);
        }
        float bv = bias[f];
        #pragma unroll
        for (int r = 0; r < 4; r++) {
            int lrow = gg * 16 + quad * 4 + r;
            int nrow = nb0 + lrow;
            float v = fmaxf((acc0[r] + (acc1[r] + acc2[r])) + bv, 0.f);
            unsigned short h = f2bf(v);
            unsigned short l = f2bf(v - bf2f(h));
            if (nrow < N_NODES) {
                Ohi[(size_t)nrow * D + f] = h;
                Olo[(size_t)nrow * D + f] = l;
            }
        }
    }

    if (!FINAL) return;

    // ---- classifier GEMM (48 cols) + log_softmax; h2 read back from global scratch ----
    __syncthreads();   // all h2 writes of this block drained (vmcnt before barrier) + fence
    bf16x8 a3h[4], a3l[4];
    {
        const unsigned short* r3h = Ohi + (size_t)nodec * D + quad * 8;
        const unsigned short* r3l = Olo + (size_t)nodec * D + quad * 8;
        #pragma unroll
        for (int ks = 0; ks < 4; ks++) {
            a3h[ks] = *(const bf16x8*)(r3h + ks * 32);
            a3l[ks] = *(const bf16x8*)(r3l + ks * 32);
        }
    }
    // tp=0 -> tiles 0,1 (cols 0..31); tp=1 -> tile 2 (cols 32..47)
    const int ntiles = (tp == 0) ? 2 : 1;
    float res[2][4];
    #pragma unroll
    for (int t = 0; t < 2; t++) {
        if (t >= ntiles) break;
        int nt = (tp == 0) ? t : 2;
        int f = nt * 16 + m;
        const unsigned short* whirow = WLhi + (size_t)f * 256 + quad * 8;
        const unsigned short* wlorow = WLlo + (size_t)f * 256 + quad * 8;
        f32x4 acc0 = {0.f, 0.f, 0.f, 0.f};
        f32x4 acc1 = {0.f, 0.f, 0.f, 0.f};
        f32x4 acc2 = {0.f, 0.f, 0.f, 0.f};
        #pragma unroll
        for (int ks = 0; ks < 8; ks++) {
            bf16x8 bh = *(const bf16x8*)(whirow + ks * 32);
            bf16x8 bl = *(const bf16x8*)(wlorow + ks * 32);
            bf16x8 ah = (ks < 4) ? a2h[ks] : a3h[ks - 4];   // A = [h1 | h2]
            bf16x8 al = (ks < 4) ? a2l[ks] : a3l[ks - 4];
            acc0 = __builtin_amdgcn_mfma_f32_16x16x32_bf16(ah, bh, acc0, 0, 0, 0);
            acc1 = __builtin_amdgcn_mfma_f32_16x16x32_bf16(ah, bl, acc1, 0, 0, 0);
            acc2 = __builtin_amdgcn_mfma_f32_16x16x32_bf16(al, bh, acc2, 0, 0, 0);
        }
        float bv = (f < 40) ? blin[f] : 0.f;
        #pragma unroll
        for (int r = 0; r < 4; r++) res[t][r] = (acc0[r] + (acc1[r] + acc2[r])) + bv;
    }
    #pragma unroll
    for (int r = 0; r < 4; r++) {
        float pm = -INFINITY;
        #pragma unroll
        for (int t = 0; t < 2; t++) {
            if (t >= ntiles) break;
            int f = ((tp == 0) ? t : 2) * 16 + m;
            if (f < 40) pm = fmaxf(pm, res[t][r]);
        }
        #pragma unroll
        for (int o = 8; o > 0; o >>= 1) pm = fmaxf(pm, __shfl_xor(pm, o, 64));
        if (m == 0) stats[tp * 64 + gg * 16 + quad * 4 + r] = pm;
    }
    __syncthreads();
    float gm[4];
    #pragma unroll
    for (int r = 0; r < 4; r++) {
        int row = gg * 16 + quad * 4 + r;
        gm[r] = fmaxf(stats[row], stats[64 + row]);
        float ps = 0.f;
        #pragma unroll
        for (int t = 0; t < 2; t++) {
            if (t >= ntiles) break;
            int f = ((tp == 0) ? t : 2) * 16 + m;
            if (f < 40) ps += expf(res[t][r] - gm[r]);
        }
        #pragma unroll
        for (int o = 8; o > 0; o >>= 1) ps += __shfl_xor(ps, o, 64);
        if (m == 0) stats[128 + tp * 64 + row] = ps;
    }
    __syncthreads();
    #pragma unroll
    for (int r = 0; r < 4; r++) {
        int row = gg * 16 + quad * 4 + r;
        int nrow = nb0 + row;
        if (nrow >= N_NODES) continue;
        float lse = gm[r] + logf(stats[128 + row] + stats[192 + row]);
        #pragma unroll
        for (int t = 0; t < 2; t++) {
            if (t >= ntiles) break;
            int f = ((tp == 0) ? t : 2) * 16 + m;
            if (f < 40) out[(size_t)nrow * 40 + f] = res[t][r] - lse;
        }
    }
}

extern "C" void kernel_launch(void* const* d_in, const int* in_sizes, int n_in,
                              void* d_out, int out_size, void* d_ws, size_t ws_size,
                              hipStream_t stream) {
    const float* x     = (const float*)d_in[0];
    const int*   ei    = (const int*)d_in[1];
    const int*   src   = ei;
    const int*   dst   = ei + N_EDGES;
    const float* W1_l  = (const float*)d_in[2];
    const float* b1_l  = (const float*)d_in[3];
    const float* W1_r  = (const float*)d_in[4];
    const float* W2_l  = (const float*)d_in[5];
    const float* b2_l  = (const float*)d_in[6];
    const float* W2_r  = (const float*)d_in[7];
    const float* W_lin = (const float*)d_in[8];
    const float* b_lin = (const float*)d_in[9];
    float* out = (float*)d_out;

    const size_t nd = (size_t)N_NODES * D;
    unsigned short* xhi  = (unsigned short*)d_ws;
    unsigned short* xlo  = xhi + nd;
    unsigned short* h1hi = xlo + nd;
    unsigned short* h1lo = h1hi + nd;
    unsigned short* W1hi = h1lo + nd;                // 128*256 bf16 each
    unsigned short* W1lo = W1hi + 128 * 256;
    unsigned short* W2hi = W1lo + 128 * 256;
    unsigned short* W2lo = W2hi + 128 * 256;
    unsigned short* WLhi = W2lo + 128 * 256;         // 48*256
    unsigned short* WLlo = WLhi + 48 * 256;
    int* deg    = (int*)(WLlo + 48 * 256);
    int* rowptr = deg + N_NODES;                     // N_NODES+1
    int* rank   = rowptr + N_NODES + 1;              // N_EDGES
    int* srcs_sorted = rank + N_EDGES;               // N_EDGES
    int* bsum   = srcs_sorted + N_EDGES;             // NBLK
    unsigned short* aghi = (unsigned short*)(bsum + NBLK);   // agg planes (reused both layers)
    unsigned short* aglo = aghi + nd;
    unsigned short* h2hi = aglo + nd;                // h2 scratch (FINAL)
    unsigned short* h2lo = h2hi + nd;

    // ---- prep (casts/splits) + degree/rank histogram in one dispatch ----
    hipMemsetAsync(deg, 0, N_NODES * sizeof(int), stream);
    prep_deg_kernel<<<9551, 256, 0, stream>>>(dst, deg, rank, x, W1_l, W1_r, W2_l, W2_r, W_lin,
                                              xhi, xlo, W1hi, W1lo, W2hi, W2lo, WLhi, WLlo);

    // ---- CSR build ----
    scan_partial<<<NBLK, 256, 0, stream>>>(deg, bsum);
    scan_write<<<NBLK, 256, 0, stream>>>(deg, bsum, rowptr);
    bucket_kernel<<<(N_EDGES + 255) / 256, 256, 0, stream>>>(src, dst, rowptr, rank, srcs_sorted);

    const int lblk = (N_NODES + 63) / 64;

    // ---- layer 1 ----
    gather_mean<<<GATHER_BLOCKS, 256, 0, stream>>>(srcs_sorted, rowptr, xhi, aghi, aglo);
    gemm_layer<false><<<lblk, 512, 0, stream>>>(aghi, aglo, xhi, xlo,
                                                W1hi, W1lo, b1_l, h1hi, h1lo,
                                                nullptr, nullptr, nullptr, nullptr);
    // ---- layer 2 + classifier + log_softmax (h2 via global scratch) ----
    gather_mean<<<GATHER_BLOCKS, 256, 0, stream>>>(srcs_sorted, rowptr, h1hi, aghi, aglo);
    gemm_layer<true><<<lblk, 512, 0, stream>>>(aghi, aglo, h1hi, h1lo,
                                               W2hi, W2lo, b2_l, h2hi, h2lo,
                                               WLhi, WLlo, b_lin, out);
}

// Round 6
// 328.160 us; speedup vs baseline: 1.0390x; 1.0390x over previous
//
#include <hip/hip_runtime.h>
#include <math.h>

#define N_NODES 50000
#define N_EDGES 800000
#define D 128
#define NBLK 196   // ceil(N_NODES/256)
#define GATHER_BLOCKS 2048

typedef __attribute__((ext_vector_type(8))) short bf16x8;
typedef __attribute__((ext_vector_type(4))) float f32x4;
typedef __attribute__((ext_vector_type(4))) unsigned int u32x4;

static __device__ __forceinline__ unsigned short f2bf(float f) {
    unsigned int u = __float_as_uint(f);
    u = (u + 0x7fffu + ((u >> 16) & 1u)) >> 16;
    return (unsigned short)u;
}
static __device__ __forceinline__ float bf2f(unsigned short h) {
    return __uint_as_float(((unsigned int)h) << 16);
}

// ---------------- fused prep: degree+rank histogram + split x + weight split-casts ----------------
__global__ void prep_deg_kernel(const int* __restrict__ dst, int* __restrict__ deg,
                                int* __restrict__ rank,
                                const float* __restrict__ x,
                                const float* __restrict__ W1l, const float* __restrict__ W1r,
                                const float* __restrict__ W2l, const float* __restrict__ W2r,
                                const float* __restrict__ Wlin,
                                unsigned short* __restrict__ xhi, unsigned short* __restrict__ xlo,
                                unsigned short* __restrict__ W1hi, unsigned short* __restrict__ W1lo,
                                unsigned short* __restrict__ W2hi, unsigned short* __restrict__ W2lo,
                                unsigned short* __restrict__ WLhi, unsigned short* __restrict__ WLlo) {
    int b = blockIdx.x, tid = threadIdx.x;
    if (b < 3125) {
        int e = b * 256 + tid;
        rank[e] = atomicAdd(&deg[dst[e]], 1);   // rank within dst bucket
    } else if (b < 9375) {
        int i = ((b - 3125) * 256 + tid) * 4;
        float4 v = *(const float4*)(x + i);
        ushort4 h, l;
        h.x = f2bf(v.x); l.x = f2bf(v.x - bf2f(h.x));
        h.y = f2bf(v.y); l.y = f2bf(v.y - bf2f(h.y));
        h.z = f2bf(v.z); l.z = f2bf(v.z - bf2f(h.z));
        h.w = f2bf(v.w); l.w = f2bf(v.w - bf2f(h.w));
        *(ushort4*)(xhi + i) = h;
        *(ushort4*)(xlo + i) = l;
    } else if (b < 9503) {
        int isW2 = (b >= 9439);
        const float* A = isW2 ? W2l : W1l;
        const float* B = isW2 ? W2r : W1r;
        unsigned short* hi = isW2 ? W2hi : W1hi;
        unsigned short* lo = isW2 ? W2lo : W1lo;
        int f = (b - (isW2 ? 9439 : 9375)) * 2 + (tid >> 7);
        int t = tid & 127;
        float va = A[f * 128 + t], vb = B[f * 128 + t];
        unsigned short ha = f2bf(va), hb = f2bf(vb);
        hi[f * 256 + t]       = ha;
        hi[f * 256 + 128 + t] = hb;
        lo[f * 256 + t]       = f2bf(va - bf2f(ha));
        lo[f * 256 + 128 + t] = f2bf(vb - bf2f(hb));
    } else {
        int f = b - 9503;
        float v = (f < 40) ? Wlin[f * 256 + tid] : 0.f;
        unsigned short h = f2bf(v);
        WLhi[f * 256 + tid] = h;
        WLlo[f * 256 + tid] = f2bf(v - bf2f(h));
    }
}

// ---------------- 2-stage scan ----------------
__global__ void scan_partial(const int* __restrict__ deg, int* __restrict__ bsum) {
    __shared__ int wt[4];
    int tid = threadIdx.x, lane = tid & 63, wv = tid >> 6;
    int idx = blockIdx.x * 256 + tid;
    int v = (idx < N_NODES) ? deg[idx] : 0;
    int s = v;
    #pragma unroll
    for (int o = 1; o < 64; o <<= 1) s += __shfl_xor(s, o, 64);
    if (lane == 0) wt[wv] = s;
    __syncthreads();
    if (tid == 0) bsum[blockIdx.x] = wt[0] + wt[1] + wt[2] + wt[3];
}

__global__ void scan_write(const int* __restrict__ deg, const int* __restrict__ bsum,
                           int* __restrict__ rowptr) {
    __shared__ int wt[4], wt2[4];
    int tid = threadIdx.x, lane = tid & 63, wv = tid >> 6;
    int v0 = (tid < blockIdx.x) ? bsum[tid] : 0;   // blockIdx.x <= 195 < 256
    int s0 = v0;
    #pragma unroll
    for (int o = 1; o < 64; o <<= 1) s0 += __shfl_xor(s0, o, 64);
    if (lane == 0) wt2[wv] = s0;
    int idx = blockIdx.x * 256 + tid;
    int v = (idx < N_NODES) ? deg[idx] : 0;
    int s = v;
    #pragma unroll
    for (int o = 1; o < 64; o <<= 1) { int t = __shfl_up(s, o, 64); if (lane >= o) s += t; }
    if (lane == 63) wt[wv] = s;
    __syncthreads();
    int boff = wt2[0] + wt2[1] + wt2[2] + wt2[3];
    #pragma unroll
    for (int w = 0; w < 4; w++) boff += (w < wv) ? wt[w] : 0;
    int excl = boff + s - v;
    if (idx < N_NODES) rowptr[idx] = excl;
    if (idx == 0) rowptr[N_NODES] = N_EDGES;
}

// ---------------- bucket edges by dst (atomic-free: pos = rowptr[dst] + rank) ----------------
__global__ void bucket_kernel(const int* __restrict__ src, const int* __restrict__ dst,
                              const int* __restrict__ rowptr, const int* __restrict__ rank,
                              int* __restrict__ srcs_sorted) {
    int e = blockIdx.x * blockDim.x + threadIdx.x;
    if (e < N_EDGES) {
        srcs_sorted[rowptr[dst[e]] + rank[e]] = src[e];
    }
}

// ---------------- gather-mean kernel (no LDS -> 32 waves/CU) ----------------
__global__ __launch_bounds__(256, 8) void gather_mean(
    const int* __restrict__ srcs, const int* __restrict__ rowptr,
    const unsigned short* __restrict__ Shi,
    unsigned short* __restrict__ Aghi, unsigned short* __restrict__ Aglo)
{
    const int tid = threadIdx.x;
    const int wv = tid >> 6, lane = tid & 63;
    const int g = lane >> 4, q = lane & 15;
    const int qb = q << 4;
    const char* xb = (const char*)Shi;          // row = 256 bytes
    const int wid = blockIdx.x * 4 + wv;
    const int NW = GATHER_BLOCKS * 4;
    #pragma unroll 1
    for (int p = wid; p < N_NODES / 2; p += NW) {
        const int nA = 2 * p, nB = 2 * p + 1;
        const int begA = rowptr[nA];
        const int endA = rowptr[nA + 1];
        const int endB = rowptr[nB + 1];
        const int begB = endA;
        const int degA = endA - begA, degB = endB - begB;
        float ax[4] = {0,0,0,0}, ay[4] = {0,0,0,0};
        float bx[4] = {0,0,0,0}, by[4] = {0,0,0,0};
        int nsA = (degA + 63) >> 6, nsB = (degB + 63) >> 6;
        int nsmax = max(nsA, nsB);
        #pragma unroll 1
        for (int st = 0; st < nsmax; st++) {
            int svA = 0, svB = 0, nbA = 0, nbB = 0;
            if (st < nsA) {                     // wave-uniform branch
                int sb = begA + (st << 6);
                nbA = min(64, endA - sb);
                svA = srcs[min(sb + lane, endA - 1)];   // 64 edge ids, coalesced
            }
            if (st < nsB) {
                int sb = begB + (st << 6);
                nbB = min(64, endB - sb);
                svB = srcs[min(sb + lane, endB - 1)];
            }
            int itA = (nbA + 3) >> 2, itB = (nbB + 3) >> 2;
            int itmax = max(itA, itB);
            #pragma unroll 2
            for (int b = 0; b < itmax; b++) {
                int ei = (b << 2) + g;          // edge slot within strip for this group
                if (b < itA) {                  // wave-uniform
                    unsigned sv = (unsigned)__shfl(svA, ei, 64);
                    u32x4 v = *(const u32x4*)(xb + ((sv << 8) + qb));
                    v.x = (ei < nbA) ? v.x : 0u;
                    v.y = (ei < nbA) ? v.y : 0u;
                    v.z = (ei < nbA) ? v.z : 0u;
                    v.w = (ei < nbA) ? v.w : 0u;
                    ax[0] += __uint_as_float(v.x << 16); ay[0] += __uint_as_float(v.x & 0xffff0000u);
                    ax[1] += __uint_as_float(v.y << 16); ay[1] += __uint_as_float(v.y & 0xffff0000u);
                    ax[2] += __uint_as_float(v.z << 16); ay[2] += __uint_as_float(v.z & 0xffff0000u);
                    ax[3] += __uint_as_float(v.w << 16); ay[3] += __uint_as_float(v.w & 0xffff0000u);
                }
                if (b < itB) {
                    unsigned sv = (unsigned)__shfl(svB, ei, 64);
                    u32x4 v = *(const u32x4*)(xb + ((sv << 8) + qb));
                    v.x = (ei < nbB) ? v.x : 0u;
                    v.y = (ei < nbB) ? v.y : 0u;
                    v.z = (ei < nbB) ? v.z : 0u;
                    v.w = (ei < nbB) ? v.w : 0u;
                    bx[0] += __uint_as_float(v.x << 16); by[0] += __uint_as_float(v.x & 0xffff0000u);
                    bx[1] += __uint_as_float(v.y << 16); by[1] += __uint_as_float(v.y & 0xffff0000u);
                    bx[2] += __uint_as_float(v.z << 16); by[2] += __uint_as_float(v.z & 0xffff0000u);
                    bx[3] += __uint_as_float(v.w << 16); by[3] += __uint_as_float(v.w & 0xffff0000u);
                }
            }
        }
        // cross-group reduce: lanes {l, l^16, l^32, l^48} hold partials of the same features
        #pragma unroll
        for (int d = 0; d < 4; d++) {
            ax[d] += __shfl_xor(ax[d], 16, 64); ax[d] += __shfl_xor(ax[d], 32, 64);
            ay[d] += __shfl_xor(ay[d], 16, 64); ay[d] += __shfl_xor(ay[d], 32, 64);
            bx[d] += __shfl_xor(bx[d], 16, 64); bx[d] += __shfl_xor(bx[d], 32, 64);
            by[d] += __shfl_xor(by[d], 16, 64); by[d] += __shfl_xor(by[d], 32, 64);
        }
        if (g == 0) {   // 16 lanes write one u32x4 per plane per node (coalesced 256 B)
            float invA = 1.0f / fmaxf((float)degA, 1.0f);
            float invB = 1.0f / fmaxf((float)degB, 1.0f);
            u32x4 ha, la, hb, lb;
            #pragma unroll
            for (int d = 0; d < 4; d++) {
                float sx = ax[d] * invA, sy = ay[d] * invA;
                unsigned short h0 = f2bf(sx), h1 = f2bf(sy);
                unsigned short l0 = f2bf(sx - bf2f(h0)), l1 = f2bf(sy - bf2f(h1));
                ha[d] = (unsigned)h0 | ((unsigned)h1 << 16);
                la[d] = (unsigned)l0 | ((unsigned)l1 << 16);
                float tx = bx[d] * invB, ty = by[d] * invB;
                unsigned short h2 = f2bf(tx), h3 = f2bf(ty);
                unsigned short l2 = f2bf(tx - bf2f(h2)), l3 = f2bf(ty - bf2f(h3));
                hb[d] = (unsigned)h2 | ((unsigned)h3 << 16);
                lb[d] = (unsigned)l2 | ((unsigned)l3 << 16);
            }
            *(u32x4*)(Aghi + (size_t)nA * D + q * 8) = ha;
            *(u32x4*)(Aglo + (size_t)nA * D + q * 8) = la;
            *(u32x4*)(Aghi + (size_t)nB * D + q * 8) = hb;
            *(u32x4*)(Aglo + (size_t)nB * D + q * 8) = lb;
        }
    }
}

// ---------------- GEMM kernel: 256-thr (4-wave) blocks, 32 nodes x 128 f ----------------
// Round-5 diagnosis: 512-thr blocks cap residency at ~3 blocks/CU -> 768 < 782 grid ->
// two rounds of ~40 us latency-dominated blocks, occupancy ~30%. Now: 4 waves/block,
// grid 1563, LDS 17.4 KB, VGPR ~60 -> 8 blocks/CU = 32 waves (100% slots), whole grid
// co-resident in ONE round, barrier width halved, 2x independent blocks to overlap stalls.
// Wave (gg,tp): gg=wv&1 node half (16 nodes), tp=wv>>1 f half of the 32-f quarter.
// Whi staged in LDS (round-2 A/B). h2 via global scratch (keeps LDS small).
template<bool FINAL>
__global__ __launch_bounds__(256, 4) void gemm_layer(
    const unsigned short* __restrict__ Aghi, const unsigned short* __restrict__ Aglo,  // agg planes
    const unsigned short* __restrict__ A2hi, const unsigned short* __restrict__ A2lo,  // self planes
    const unsigned short* __restrict__ Whi, const unsigned short* __restrict__ Wlo,    // [128,256]
    const float* __restrict__ bias,
    unsigned short* __restrict__ Ohi, unsigned short* __restrict__ Olo,         // layer out / h2 scratch
    const unsigned short* __restrict__ WLhi, const unsigned short* __restrict__ WLlo,  // [48,256]
    const float* __restrict__ blin, float* __restrict__ out)                    // (if FINAL)
{
    __shared__ unsigned short Wl[8192];                 // 16 KB (Whi quarter stage)
    __shared__ float stats[256];                        // softmax stats (FINAL)

    const int tid = threadIdx.x;
    const int wv = tid >> 6, lane = tid & 63;
    const int nb0 = blockIdx.x * 32;
    const int m = lane & 15, quad = lane >> 4;
    const int gg = wv & 1, tp = wv >> 1;
    const int nodec = min(nb0 + gg * 16 + m, N_NODES - 1);

    // A1 frags (agg, K 0..127) + A2 frags (self, K 128..255) from global
    bf16x8 a1h[4], a1l[4], a2h[4], a2l[4];
    {
        const unsigned short* r1h = Aghi + (size_t)nodec * D + quad * 8;
        const unsigned short* r1l = Aglo + (size_t)nodec * D + quad * 8;
        const unsigned short* r2h = A2hi + (size_t)nodec * D + quad * 8;
        const unsigned short* r2l = A2lo + (size_t)nodec * D + quad * 8;
        #pragma unroll
        for (int ks = 0; ks < 4; ks++) {
            a1h[ks] = *(const bf16x8*)(r1h + ks * 32);
            a1l[ks] = *(const bf16x8*)(r1l + ks * 32);
            a2h[ks] = *(const bf16x8*)(r2h + ks * 32);
            a2l[ks] = *(const bf16x8*)(r2l + ks * 32);
        }
    }

    // ---- GEMM over 4 f-quarters (Whi staged 16 KB at a time; 4 stage iters at 256 thr) ----
    #pragma unroll 1
    for (int fq = 0; fq < 4; fq++) {
        const int f0 = fq * 32;
        if (fq) __syncthreads();
        #pragma unroll
        for (int itS = 0; itS < 4; itS++) {
            int c = tid + itS * 256;                 // 1024 chunks of 16B
            int nt = c >> 9, w2 = c & 511;
            int ks = w2 >> 6, lidx = w2 & 63;
            int mm = lidx >> 2, qq = lidx & 3;
            const unsigned short* gp = Whi + (size_t)(f0 + nt * 16 + mm) * 256 + ks * 32 + qq * 8;
            *(bf16x8*)&Wl[(size_t)c * 8] = *(const bf16x8*)gp;
        }
        __syncthreads();

        int f = f0 + tp * 16 + m;
        const unsigned short* wlorow = Wlo + (size_t)f * 256 + quad * 8;
        f32x4 acc0 = {0.f, 0.f, 0.f, 0.f};
        f32x4 acc1 = {0.f, 0.f, 0.f, 0.f};
        f32x4 acc2 = {0.f, 0.f, 0.f, 0.f};
        #pragma unroll
        for (int ks = 0; ks < 8; ks++) {
            bf16x8 bh = *(const bf16x8*)&Wl[(size_t)(((tp * 8 + ks) << 6) + (m * 4 + quad)) * 8];
            bf16x8 bl = *(const bf16x8*)(wlorow + ks * 32);
            bf16x8 ah = (ks < 4) ? a1h[ks] : a2h[ks - 4];
            bf16x8 al = (ks < 4) ? a1l[ks] : a2l[ks - 4];
            acc0 = __builtin_amdgcn_mfma_f32_16x16x32_bf16(ah, bh, acc0, 0, 0, 0);
            acc1 = __builtin_amdgcn_mfma_f32_16x16x32_bf16(ah, bl, acc1, 0, 0, 0);
            acc2 = __builtin_amdgcn_mfma_f32_16x16x32_bf16(al, bh, acc2, 0, 0, 0);
        }
        float bv = bias[f];
        #pragma unroll
        for (int r = 0; r < 4; r++) {
            int lrow = gg * 16 + quad * 4 + r;
            int nrow = nb0 + lrow;
            float v = fmaxf((acc0[r] + (acc1[r] + acc2[r])) + bv, 0.f);
            unsigned short h = f2bf(v);
            unsigned short l = f2bf(v - bf2f(h));
            if (nrow < N_NODES) {
                Ohi[(size_t)nrow * D + f] = h;
                Olo[(size_t)nrow * D + f] = l;
            }
        }
    }

    if (!FINAL) return;

    // ---- classifier GEMM (48 cols) + log_softmax; h2 read back from global scratch ----
    __syncthreads();   // this block's h2 writes drained (vmcnt(0) before barrier)
    bf16x8 a3h[4], a3l[4];
    {
        const unsigned short* r3h = Ohi + (size_t)nodec * D + quad * 8;
        const unsigned short* r3l = Olo + (size_t)nodec * D + quad * 8;
        #pragma unroll
        for (int ks = 0; ks < 4; ks++) {
            a3h[ks] = *(const bf16x8*)(r3h + ks * 32);
            a3l[ks] = *(const bf16x8*)(r3l + ks * 32);
        }
    }
    // tp=0 -> tiles 0,1 (cols 0..31); tp=1 -> tile 2 (cols 32..47)
    const int ntiles = (tp == 0) ? 2 : 1;
    float res[2][4];
    #pragma unroll
    for (int t = 0; t < 2; t++) {
        if (t >= ntiles) break;
        int nt = (tp == 0) ? t : 2;
        int f = nt * 16 + m;
        const unsigned short* whirow = WLhi + (size_t)f * 256 + quad * 8;
        const unsigned short* wlorow = WLlo + (size_t)f * 256 + quad * 8;
        f32x4 acc0 = {0.f, 0.f, 0.f, 0.f};
        f32x4 acc1 = {0.f, 0.f, 0.f, 0.f};
        f32x4 acc2 = {0.f, 0.f, 0.f, 0.f};
        #pragma unroll
        for (int ks = 0; ks < 8; ks++) {
            bf16x8 bh = *(const bf16x8*)(whirow + ks * 32);
            bf16x8 bl = *(const bf16x8*)(wlorow + ks * 32);
            bf16x8 ah = (ks < 4) ? a2h[ks] : a3h[ks - 4];   // A = [h1 | h2]
            bf16x8 al = (ks < 4) ? a2l[ks] : a3l[ks - 4];
            acc0 = __builtin_amdgcn_mfma_f32_16x16x32_bf16(ah, bh, acc0, 0, 0, 0);
            acc1 = __builtin_amdgcn_mfma_f32_16x16x32_bf16(ah, bl, acc1, 0, 0, 0);
            acc2 = __builtin_amdgcn_mfma_f32_16x16x32_bf16(al, bh, acc2, 0, 0, 0);
        }
        float bv = (f < 40) ? blin[f] : 0.f;
        #pragma unroll
        for (int r = 0; r < 4; r++) res[t][r] = (acc0[r] + (acc1[r] + acc2[r])) + bv;
    }
    #pragma unroll
    for (int r = 0; r < 4; r++) {
        float pm = -INFINITY;
        #pragma unroll
        for (int t = 0; t < 2; t++) {
            if (t >= ntiles) break;
            int f = ((tp == 0) ? t : 2) * 16 + m;
            if (f < 40) pm = fmaxf(pm, res[t][r]);
        }
        #pragma unroll
        for (int o = 8; o > 0; o >>= 1) pm = fmaxf(pm, __shfl_xor(pm, o, 64));
        if (m == 0) stats[tp * 64 + gg * 16 + quad * 4 + r] = pm;
    }
    __syncthreads();
    float gm[4];
    #pragma unroll
    for (int r = 0; r < 4; r++) {
        int row = gg * 16 + quad * 4 + r;          // 0..31
        gm[r] = fmaxf(stats[row], stats[64 + row]);
        float ps = 0.f;
        #pragma unroll
        for (int t = 0; t < 2; t++) {
            if (t >= ntiles) break;
            int f = ((tp == 0) ? t : 2) * 16 + m;
            if (f < 40) ps += expf(res[t][r] - gm[r]);
        }
        #pragma unroll
        for (int o = 8; o > 0; o >>= 1) ps += __shfl_xor(ps, o, 64);
        if (m == 0) stats[128 + tp * 64 + row] = ps;
    }
    __syncthreads();
    #pragma unroll
    for (int r = 0; r < 4; r++) {
        int row = gg * 16 + quad * 4 + r;
        int nrow = nb0 + row;
        if (nrow >= N_NODES) continue;
        float lse = gm[r] + logf(stats[128 + row] + stats[192 + row]);
        #pragma unroll
        for (int t = 0; t < 2; t++) {
            if (t >= ntiles) break;
            int f = ((tp == 0) ? t : 2) * 16 + m;
            if (f < 40) out[(size_t)nrow * 40 + f] = res[t][r] - lse;
        }
    }
}

extern "C" void kernel_launch(void* const* d_in, const int* in_sizes, int n_in,
                              void* d_out, int out_size, void* d_ws, size_t ws_size,
                              hipStream_t stream) {
    const float* x     = (const float*)d_in[0];
    const int*   ei    = (const int*)d_in[1];
    const int*   src   = ei;
    const int*   dst   = ei + N_EDGES;
    const float* W1_l  = (const float*)d_in[2];
    const float* b1_l  = (const float*)d_in[3];
    const float* W1_r  = (const float*)d_in[4];
    const float* W2_l  = (const float*)d_in[5];
    const float* b2_l  = (const float*)d_in[6];
    const float* W2_r  = (const float*)d_in[7];
    const float* W_lin = (const float*)d_in[8];
    const float* b_lin = (const float*)d_in[9];
    float* out = (float*)d_out;

    const size_t nd = (size_t)N_NODES * D;
    unsigned short* xhi  = (unsigned short*)d_ws;
    unsigned short* xlo  = xhi + nd;
    unsigned short* h1hi = xlo + nd;
    unsigned short* h1lo = h1hi + nd;
    unsigned short* W1hi = h1lo + nd;                // 128*256 bf16 each
    unsigned short* W1lo = W1hi + 128 * 256;
    unsigned short* W2hi = W1lo + 128 * 256;
    unsigned short* W2lo = W2hi + 128 * 256;
    unsigned short* WLhi = W2lo + 128 * 256;         // 48*256
    unsigned short* WLlo = WLhi + 48 * 256;
    int* deg    = (int*)(WLlo + 48 * 256);
    int* rowptr = deg + N_NODES;                     // N_NODES+1
    int* rank   = rowptr + N_NODES + 1;              // N_EDGES
    int* srcs_sorted = rank + N_EDGES;               // N_EDGES
    int* bsum   = srcs_sorted + N_EDGES;             // NBLK
    unsigned short* aghi = (unsigned short*)(bsum + NBLK);   // agg planes (reused both layers)
    unsigned short* aglo = aghi + nd;
    unsigned short* h2hi = aglo + nd;                // h2 scratch (FINAL)
    unsigned short* h2lo = h2hi + nd;

    // ---- prep (casts/splits) + degree/rank histogram in one dispatch ----
    hipMemsetAsync(deg, 0, N_NODES * sizeof(int), stream);
    prep_deg_kernel<<<9551, 256, 0, stream>>>(dst, deg, rank, x, W1_l, W1_r, W2_l, W2_r, W_lin,
                                              xhi, xlo, W1hi, W1lo, W2hi, W2lo, WLhi, WLlo);

    // ---- CSR build ----
    scan_partial<<<NBLK, 256, 0, stream>>>(deg, bsum);
    scan_write<<<NBLK, 256, 0, stream>>>(deg, bsum, rowptr);
    bucket_kernel<<<(N_EDGES + 255) / 256, 256, 0, stream>>>(src, dst, rowptr, rank, srcs_sorted);

    const int lblk = (N_NODES + 31) / 32;            // 1563 blocks of 32 nodes

    // ---- layer 1 ----
    gather_mean<<<GATHER_BLOCKS, 256, 0, stream>>>(srcs_sorted, rowptr, xhi, aghi, aglo);
    gemm_layer<false><<<lblk, 256, 0, stream>>>(aghi, aglo, xhi, xlo,
                                                W1hi, W1lo, b1_l, h1hi, h1lo,
                                                nullptr, nullptr, nullptr, nullptr);
    // ---- layer 2 + classifier + log_softmax (h2 via global scratch) ----
    gather_mean<<<GATHER_BLOCKS, 256, 0, stream>>>(srcs_sorted, rowptr, h1hi, aghi, aglo);
    gemm_layer<true><<<lblk, 256, 0, stream>>>(aghi, aglo, h1hi, h1lo,
                                               W2hi, W2lo, b2_l, h2hi, h2lo,
                                               WLhi, WLlo, b_lin, out);
}

// Round 7
// 302.725 us; speedup vs baseline: 1.1263x; 1.0840x over previous
//
#include <hip/hip_runtime.h>
#include <math.h>

#define N_NODES 50000
#define N_EDGES 800000
#define D 128
#define NBLK 196   // ceil(N_NODES/256)
#define GATHER_BLOCKS 2048

typedef __attribute__((ext_vector_type(8))) short bf16x8;
typedef __attribute__((ext_vector_type(4))) float f32x4;
typedef __attribute__((ext_vector_type(4))) unsigned int u32x4;

static __device__ __forceinline__ unsigned short f2bf(float f) {
    unsigned int u = __float_as_uint(f);
    u = (u + 0x7fffu + ((u >> 16) & 1u)) >> 16;
    return (unsigned short)u;
}
static __device__ __forceinline__ float bf2f(unsigned short h) {
    return __uint_as_float(((unsigned int)h) << 16);
}

// ---------------- fused prep: degree+rank histogram + split x + weight split-casts ----------------
__global__ void prep_deg_kernel(const int* __restrict__ dst, int* __restrict__ deg,
                                int* __restrict__ rank,
                                const float* __restrict__ x,
                                const float* __restrict__ W1l, const float* __restrict__ W1r,
                                const float* __restrict__ W2l, const float* __restrict__ W2r,
                                const float* __restrict__ Wlin,
                                unsigned short* __restrict__ xhi, unsigned short* __restrict__ xlo,
                                unsigned short* __restrict__ W1hi, unsigned short* __restrict__ W1lo,
                                unsigned short* __restrict__ W2hi, unsigned short* __restrict__ W2lo,
                                unsigned short* __restrict__ WLhi, unsigned short* __restrict__ WLlo) {
    int b = blockIdx.x, tid = threadIdx.x;
    if (b < 3125) {
        int e = b * 256 + tid;
        rank[e] = atomicAdd(&deg[dst[e]], 1);   // rank within dst bucket
    } else if (b < 9375) {
        int i = ((b - 3125) * 256 + tid) * 4;
        float4 v = *(const float4*)(x + i);
        ushort4 h, l;
        h.x = f2bf(v.x); l.x = f2bf(v.x - bf2f(h.x));
        h.y = f2bf(v.y); l.y = f2bf(v.y - bf2f(h.y));
        h.z = f2bf(v.z); l.z = f2bf(v.z - bf2f(h.z));
        h.w = f2bf(v.w); l.w = f2bf(v.w - bf2f(h.w));
        *(ushort4*)(xhi + i) = h;
        *(ushort4*)(xlo + i) = l;
    } else if (b < 9503) {
        int isW2 = (b >= 9439);
        const float* A = isW2 ? W2l : W1l;
        const float* B = isW2 ? W2r : W1r;
        unsigned short* hi = isW2 ? W2hi : W1hi;
        unsigned short* lo = isW2 ? W2lo : W1lo;
        int f = (b - (isW2 ? 9439 : 9375)) * 2 + (tid >> 7);
        int t = tid & 127;
        float va = A[f * 128 + t], vb = B[f * 128 + t];
        unsigned short ha = f2bf(va), hb = f2bf(vb);
        hi[f * 256 + t]       = ha;
        hi[f * 256 + 128 + t] = hb;
        lo[f * 256 + t]       = f2bf(va - bf2f(ha));
        lo[f * 256 + 128 + t] = f2bf(vb - bf2f(hb));
    } else {
        int f = b - 9503;
        float v = (f < 40) ? Wlin[f * 256 + tid] : 0.f;
        unsigned short h = f2bf(v);
        WLhi[f * 256 + tid] = h;
        WLlo[f * 256 + tid] = f2bf(v - bf2f(h));
    }
}

// ---------------- 2-stage scan ----------------
__global__ void scan_partial(const int* __restrict__ deg, int* __restrict__ bsum) {
    __shared__ int wt[4];
    int tid = threadIdx.x, lane = tid & 63, wv = tid >> 6;
    int idx = blockIdx.x * 256 + tid;
    int v = (idx < N_NODES) ? deg[idx] : 0;
    int s = v;
    #pragma unroll
    for (int o = 1; o < 64; o <<= 1) s += __shfl_xor(s, o, 64);
    if (lane == 0) wt[wv] = s;
    __syncthreads();
    if (tid == 0) bsum[blockIdx.x] = wt[0] + wt[1] + wt[2] + wt[3];
}

__global__ void scan_write(const int* __restrict__ deg, const int* __restrict__ bsum,
                           int* __restrict__ rowptr) {
    __shared__ int wt[4], wt2[4];
    int tid = threadIdx.x, lane = tid & 63, wv = tid >> 6;
    int v0 = (tid < blockIdx.x) ? bsum[tid] : 0;   // blockIdx.x <= 195 < 256
    int s0 = v0;
    #pragma unroll
    for (int o = 1; o < 64; o <<= 1) s0 += __shfl_xor(s0, o, 64);
    if (lane == 0) wt2[wv] = s0;
    int idx = blockIdx.x * 256 + tid;
    int v = (idx < N_NODES) ? deg[idx] : 0;
    int s = v;
    #pragma unroll
    for (int o = 1; o < 64; o <<= 1) { int t = __shfl_up(s, o, 64); if (lane >= o) s += t; }
    if (lane == 63) wt[wv] = s;
    __syncthreads();
    int boff = wt2[0] + wt2[1] + wt2[2] + wt2[3];
    #pragma unroll
    for (int w = 0; w < 4; w++) boff += (w < wv) ? wt[w] : 0;
    int excl = boff + s - v;
    if (idx < N_NODES) rowptr[idx] = excl;
    if (idx == 0) rowptr[N_NODES] = N_EDGES;
}

// ---------------- bucket edges by dst (atomic-free: pos = rowptr[dst] + rank) ----------------
__global__ void bucket_kernel(const int* __restrict__ src, const int* __restrict__ dst,
                              const int* __restrict__ rowptr, const int* __restrict__ rank,
                              int* __restrict__ srcs_sorted) {
    int e = blockIdx.x * blockDim.x + threadIdx.x;
    if (e < N_EDGES) {
        srcs_sorted[rowptr[dst[e]] + rank[e]] = src[e];
    }
}

// ---------------- gather-mean kernel (no LDS -> 32 waves/CU) ----------------
__global__ __launch_bounds__(256, 8) void gather_mean(
    const int* __restrict__ srcs, const int* __restrict__ rowptr,
    const unsigned short* __restrict__ Shi,
    unsigned short* __restrict__ Aghi, unsigned short* __restrict__ Aglo)
{
    const int tid = threadIdx.x;
    const int wv = tid >> 6, lane = tid & 63;
    const int g = lane >> 4, q = lane & 15;
    const int qb = q << 4;
    const char* xb = (const char*)Shi;          // row = 256 bytes
    const int wid = blockIdx.x * 4 + wv;
    const int NW = GATHER_BLOCKS * 4;
    #pragma unroll 1
    for (int p = wid; p < N_NODES / 2; p += NW) {
        const int nA = 2 * p, nB = 2 * p + 1;
        const int begA = rowptr[nA];
        const int endA = rowptr[nA + 1];
        const int endB = rowptr[nB + 1];
        const int begB = endA;
        const int degA = endA - begA, degB = endB - begB;
        float ax[4] = {0,0,0,0}, ay[4] = {0,0,0,0};
        float bx[4] = {0,0,0,0}, by[4] = {0,0,0,0};
        int nsA = (degA + 63) >> 6, nsB = (degB + 63) >> 6;
        int nsmax = max(nsA, nsB);
        #pragma unroll 1
        for (int st = 0; st < nsmax; st++) {
            int svA = 0, svB = 0, nbA = 0, nbB = 0;
            if (st < nsA) {                     // wave-uniform branch
                int sb = begA + (st << 6);
                nbA = min(64, endA - sb);
                svA = srcs[min(sb + lane, endA - 1)];   // 64 edge ids, coalesced
            }
            if (st < nsB) {
                int sb = begB + (st << 6);
                nbB = min(64, endB - sb);
                svB = srcs[min(sb + lane, endB - 1)];
            }
            int itA = (nbA + 3) >> 2, itB = (nbB + 3) >> 2;
            int itmax = max(itA, itB);
            #pragma unroll 2
            for (int b = 0; b < itmax; b++) {
                int ei = (b << 2) + g;          // edge slot within strip for this group
                if (b < itA) {                  // wave-uniform
                    unsigned sv = (unsigned)__shfl(svA, ei, 64);
                    u32x4 v = *(const u32x4*)(xb + ((sv << 8) + qb));
                    v.x = (ei < nbA) ? v.x : 0u;
                    v.y = (ei < nbA) ? v.y : 0u;
                    v.z = (ei < nbA) ? v.z : 0u;
                    v.w = (ei < nbA) ? v.w : 0u;
                    ax[0] += __uint_as_float(v.x << 16); ay[0] += __uint_as_float(v.x & 0xffff0000u);
                    ax[1] += __uint_as_float(v.y << 16); ay[1] += __uint_as_float(v.y & 0xffff0000u);
                    ax[2] += __uint_as_float(v.z << 16); ay[2] += __uint_as_float(v.z & 0xffff0000u);
                    ax[3] += __uint_as_float(v.w << 16); ay[3] += __uint_as_float(v.w & 0xffff0000u);
                }
                if (b < itB) {
                    unsigned sv = (unsigned)__shfl(svB, ei, 64);
                    u32x4 v = *(const u32x4*)(xb + ((sv << 8) + qb));
                    v.x = (ei < nbB) ? v.x : 0u;
                    v.y = (ei < nbB) ? v.y : 0u;
                    v.z = (ei < nbB) ? v.z : 0u;
                    v.w = (ei < nbB) ? v.w : 0u;
                    bx[0] += __uint_as_float(v.x << 16); by[0] += __uint_as_float(v.x & 0xffff0000u);
                    bx[1] += __uint_as_float(v.y << 16); by[1] += __uint_as_float(v.y & 0xffff0000u);
                    bx[2] += __uint_as_float(v.z << 16); by[2] += __uint_as_float(v.z & 0xffff0000u);
                    bx[3] += __uint_as_float(v.w << 16); by[3] += __uint_as_float(v.w & 0xffff0000u);
                }
            }
        }
        // cross-group reduce: lanes {l, l^16, l^32, l^48} hold partials of the same features
        #pragma unroll
        for (int d = 0; d < 4; d++) {
            ax[d] += __shfl_xor(ax[d], 16, 64); ax[d] += __shfl_xor(ax[d], 32, 64);
            ay[d] += __shfl_xor(ay[d], 16, 64); ay[d] += __shfl_xor(ay[d], 32, 64);
            bx[d] += __shfl_xor(bx[d], 16, 64); bx[d] += __shfl_xor(bx[d], 32, 64);
            by[d] += __shfl_xor(by[d], 16, 64); by[d] += __shfl_xor(by[d], 32, 64);
        }
        if (g == 0) {   // 16 lanes write one u32x4 per plane per node (coalesced 256 B)
            float invA = 1.0f / fmaxf((float)degA, 1.0f);
            float invB = 1.0f / fmaxf((float)degB, 1.0f);
            u32x4 ha, la, hb, lb;
            #pragma unroll
            for (int d = 0; d < 4; d++) {
                float sx = ax[d] * invA, sy = ay[d] * invA;
                unsigned short h0 = f2bf(sx), h1 = f2bf(sy);
                unsigned short l0 = f2bf(sx - bf2f(h0)), l1 = f2bf(sy - bf2f(h1));
                ha[d] = (unsigned)h0 | ((unsigned)h1 << 16);
                la[d] = (unsigned)l0 | ((unsigned)l1 << 16);
                float tx = bx[d] * invB, ty = by[d] * invB;
                unsigned short h2 = f2bf(tx), h3 = f2bf(ty);
                unsigned short l2 = f2bf(tx - bf2f(h2)), l3 = f2bf(ty - bf2f(h3));
                hb[d] = (unsigned)h2 | ((unsigned)h3 << 16);
                lb[d] = (unsigned)l2 | ((unsigned)l3 << 16);
            }
            *(u32x4*)(Aghi + (size_t)nA * D + q * 8) = ha;
            *(u32x4*)(Aglo + (size_t)nA * D + q * 8) = la;
            *(u32x4*)(Aghi + (size_t)nB * D + q * 8) = hb;
            *(u32x4*)(Aglo + (size_t)nB * D + q * 8) = lb;
        }
    }
}

// ---------------- GEMM kernel: 256-thr (4-wave) blocks, 32 nodes x 128 f ----------------
// Round-6 diagnosis: VGPR_Count=64 with a >=96-reg live set (16 A-frags = 64 VGPR alone)
// means the compiler hit the 64-reg/8-wave occupancy step by REMATERIALIZING the A-frag
// loads inside every f-quarter (4x A traffic, L1/L2 hits invisible in FETCH_SIZE), and
// the ks-loop also re-read Wlo 16B-scattered from global every step. This round:
//   (1) Wlo staged in LDS next to Whi (inner loop = 2 ds_read_b128 + 3 MFMA, no global),
//   (2) anti-remat asm fence pins A-frags in registers; __launch_bounds__(256,4) caps
//       VGPR at 128 (live set ~110 fits; round-1 proved exceeding the cap = spill hell).
// LDS = 32 KB exactly (stats aliases dead Wl in the FINAL tail).
template<bool FINAL>
__global__ __launch_bounds__(256, 4) void gemm_layer(
    const unsigned short* __restrict__ Aghi, const unsigned short* __restrict__ Aglo,  // agg planes
    const unsigned short* __restrict__ A2hi, const unsigned short* __restrict__ A2lo,  // self planes
    const unsigned short* __restrict__ Whi, const unsigned short* __restrict__ Wlo,    // [128,256]
    const float* __restrict__ bias,
    unsigned short* __restrict__ Ohi, unsigned short* __restrict__ Olo,         // layer out / h2 scratch
    const unsigned short* __restrict__ WLhi, const unsigned short* __restrict__ WLlo,  // [48,256]
    const float* __restrict__ blin, float* __restrict__ out)                    // (if FINAL)
{
    __shared__ unsigned short Wl[2][8192];              // 32 KB: [0]=Whi stage, [1]=Wlo stage

    const int tid = threadIdx.x;
    const int wv = tid >> 6, lane = tid & 63;
    const int nb0 = blockIdx.x * 32;
    const int m = lane & 15, quad = lane >> 4;
    const int gg = wv & 1, tp = wv >> 1;
    const int nodec = min(nb0 + gg * 16 + m, N_NODES - 1);

    // A1 frags (agg, K 0..127) + A2 frags (self, K 128..255) from global — loaded ONCE
    bf16x8 a1h[4], a1l[4], a2h[4], a2l[4];
    {
        const unsigned short* r1h = Aghi + (size_t)nodec * D + quad * 8;
        const unsigned short* r1l = Aglo + (size_t)nodec * D + quad * 8;
        const unsigned short* r2h = A2hi + (size_t)nodec * D + quad * 8;
        const unsigned short* r2l = A2lo + (size_t)nodec * D + quad * 8;
        #pragma unroll
        for (int ks = 0; ks < 4; ks++) {
            a1h[ks] = *(const bf16x8*)(r1h + ks * 32);
            a1l[ks] = *(const bf16x8*)(r1l + ks * 32);
            a2h[ks] = *(const bf16x8*)(r2h + ks * 32);
            a2l[ks] = *(const bf16x8*)(r2l + ks * 32);
        }
    }
    // anti-rematerialization fence: compiler must keep the fragments register-resident
    #pragma unroll
    for (int ks = 0; ks < 4; ks++) {
        asm volatile("" : "+v"(a1h[ks]), "+v"(a1l[ks]), "+v"(a2h[ks]), "+v"(a2l[ks]));
    }

    // ---- GEMM over 4 f-quarters (Whi+Wlo staged 32 KB at a time) ----
    #pragma unroll 1
    for (int fq = 0; fq < 4; fq++) {
        const int f0 = fq * 32;
        if (fq) __syncthreads();
        #pragma unroll
        for (int itS = 0; itS < 8; itS++) {
            int c = tid + itS * 256;                 // 2048 chunks of 16B (2 planes x 1024)
            int plane = c >> 10;
            int w3 = c & 1023;
            int nt = w3 >> 9, w2 = w3 & 511;
            int ks = w2 >> 6, lidx = w2 & 63;
            int mm = lidx >> 2, qq = lidx & 3;
            const unsigned short* base = plane ? Wlo : Whi;
            const unsigned short* gp = base + (size_t)(f0 + nt * 16 + mm) * 256 + ks * 32 + qq * 8;
            *(bf16x8*)&Wl[plane][(size_t)w3 * 8] = *(const bf16x8*)gp;
        }
        __syncthreads();

        int f = f0 + tp * 16 + m;
        f32x4 acc0 = {0.f, 0.f, 0.f, 0.f};
        f32x4 acc1 = {0.f, 0.f, 0.f, 0.f};
        f32x4 acc2 = {0.f, 0.f, 0.f, 0.f};
        #pragma unroll
        for (int ks = 0; ks < 8; ks++) {
            int idx = (((tp * 8 + ks) << 6) + (m * 4 + quad)) * 8;
            bf16x8 bh = *(const bf16x8*)&Wl[0][idx];
            bf16x8 bl = *(const bf16x8*)&Wl[1][idx];
            bf16x8 ah = (ks < 4) ? a1h[ks] : a2h[ks - 4];
            bf16x8 al = (ks < 4) ? a1l[ks] : a2l[ks - 4];
            acc0 = __builtin_amdgcn_mfma_f32_16x16x32_bf16(ah, bh, acc0, 0, 0, 0);
            acc1 = __builtin_amdgcn_mfma_f32_16x16x32_bf16(ah, bl, acc1, 0, 0, 0);
            acc2 = __builtin_amdgcn_mfma_f32_16x16x32_bf16(al, bh, acc2, 0, 0, 0);
        }
        float bv = bias[f];
        #pragma unroll
        for (int r = 0; r < 4; r++) {
            int lrow = gg * 16 + quad * 4 + r;
            int nrow = nb0 + lrow;
            float v = fmaxf((acc0[r] + (acc1[r] + acc2[r])) + bv, 0.f);
            unsigned short h = f2bf(v);
            unsigned short l = f2bf(v - bf2f(h));
            if (nrow < N_NODES) {
                Ohi[(size_t)nrow * D + f] = h;
                Olo[(size_t)nrow * D + f] = l;
            }
        }
    }

    if (!FINAL) return;

    // ---- classifier GEMM (48 cols) + log_softmax; h2 read back from global scratch ----
    __syncthreads();   // this block's h2 writes drained; Wl now dead -> reuse as stats
    float* stats = (float*)Wl;
    bf16x8 a3h[4], a3l[4];
    {
        const unsigned short* r3h = Ohi + (size_t)nodec * D + quad * 8;
        const unsigned short* r3l = Olo + (size_t)nodec * D + quad * 8;
        #pragma unroll
        for (int ks = 0; ks < 4; ks++) {
            a3h[ks] = *(const bf16x8*)(r3h + ks * 32);
            a3l[ks] = *(const bf16x8*)(r3l + ks * 32);
        }
    }
    // tp=0 -> tiles 0,1 (cols 0..31); tp=1 -> tile 2 (cols 32..47)
    const int ntiles = (tp == 0) ? 2 : 1;
    float res[2][4];
    #pragma unroll
    for (int t = 0; t < 2; t++) {
        if (t >= ntiles) break;
        int nt = (tp == 0) ? t : 2;
        int f = nt * 16 + m;
        const unsigned short* whirow = WLhi + (size_t)f * 256 + quad * 8;
        const unsigned short* wlorow = WLlo + (size_t)f * 256 + quad * 8;
        f32x4 acc0 = {0.f, 0.f, 0.f, 0.f};
        f32x4 acc1 = {0.f, 0.f, 0.f, 0.f};
        f32x4 acc2 = {0.f, 0.f, 0.f, 0.f};
        #pragma unroll
        for (int ks = 0; ks < 8; ks++) {
            bf16x8 bh = *(const bf16x8*)(whirow + ks * 32);
            bf16x8 bl = *(const bf16x8*)(wlorow + ks * 32);
            bf16x8 ah = (ks < 4) ? a2h[ks] : a3h[ks - 4];   // A = [h1 | h2]
            bf16x8 al = (ks < 4) ? a2l[ks] : a3l[ks - 4];
            acc0 = __builtin_amdgcn_mfma_f32_16x16x32_bf16(ah, bh, acc0, 0, 0, 0);
            acc1 = __builtin_amdgcn_mfma_f32_16x16x32_bf16(ah, bl, acc1, 0, 0, 0);
            acc2 = __builtin_amdgcn_mfma_f32_16x16x32_bf16(al, bh, acc2, 0, 0, 0);
        }
        float bv = (f < 40) ? blin[f] : 0.f;
        #pragma unroll
        for (int r = 0; r < 4; r++) res[t][r] = (acc0[r] + (acc1[r] + acc2[r])) + bv;
    }
    #pragma unroll
    for (int r = 0; r < 4; r++) {
        float pm = -INFINITY;
        #pragma unroll
        for (int t = 0; t < 2; t++) {
            if (t >= ntiles) break;
            int f = ((tp == 0) ? t : 2) * 16 + m;
            if (f < 40) pm = fmaxf(pm, res[t][r]);
        }
        #pragma unroll
        for (int o = 8; o > 0; o >>= 1) pm = fmaxf(pm, __shfl_xor(pm, o, 64));
        if (m == 0) stats[tp * 64 + gg * 16 + quad * 4 + r] = pm;
    }
    __syncthreads();
    float gm[4];
    #pragma unroll
    for (int r = 0; r < 4; r++) {
        int row = gg * 16 + quad * 4 + r;          // 0..31
        gm[r] = fmaxf(stats[row], stats[64 + row]);
        float ps = 0.f;
        #pragma unroll
        for (int t = 0; t < 2; t++) {
            if (t >= ntiles) break;
            int f = ((tp == 0) ? t : 2) * 16 + m;
            if (f < 40) ps += expf(res[t][r] - gm[r]);
        }
        #pragma unroll
        for (int o = 8; o > 0; o >>= 1) ps += __shfl_xor(ps, o, 64);
        if (m == 0) stats[128 + tp * 64 + row] = ps;
    }
    __syncthreads();
    #pragma unroll
    for (int r = 0; r < 4; r++) {
        int row = gg * 16 + quad * 4 + r;
        int nrow = nb0 + row;
        if (nrow >= N_NODES) continue;
        float lse = gm[r] + logf(stats[128 + row] + stats[192 + row]);
        #pragma unroll
        for (int t = 0; t < 2; t++) {
            if (t >= ntiles) break;
            int f = ((tp == 0) ? t : 2) * 16 + m;
            if (f < 40) out[(size_t)nrow * 40 + f] = res[t][r] - lse;
        }
    }
}

extern "C" void kernel_launch(void* const* d_in, const int* in_sizes, int n_in,
                              void* d_out, int out_size, void* d_ws, size_t ws_size,
                              hipStream_t stream) {
    const float* x     = (const float*)d_in[0];
    const int*   ei    = (const int*)d_in[1];
    const int*   src   = ei;
    const int*   dst   = ei + N_EDGES;
    const float* W1_l  = (const float*)d_in[2];
    const float* b1_l  = (const float*)d_in[3];
    const float* W1_r  = (const float*)d_in[4];
    const float* W2_l  = (const float*)d_in[5];
    const float* b2_l  = (const float*)d_in[6];
    const float* W2_r  = (const float*)d_in[7];
    const float* W_lin = (const float*)d_in[8];
    const float* b_lin = (const float*)d_in[9];
    float* out = (float*)d_out;

    const size_t nd = (size_t)N_NODES * D;
    unsigned short* xhi  = (unsigned short*)d_ws;
    unsigned short* xlo  = xhi + nd;
    unsigned short* h1hi = xlo + nd;
    unsigned short* h1lo = h1hi + nd;
    unsigned short* W1hi = h1lo + nd;                // 128*256 bf16 each
    unsigned short* W1lo = W1hi + 128 * 256;
    unsigned short* W2hi = W1lo + 128 * 256;
    unsigned short* W2lo = W2hi + 128 * 256;
    unsigned short* WLhi = W2lo + 128 * 256;         // 48*256
    unsigned short* WLlo = WLhi + 48 * 256;
    int* deg    = (int*)(WLlo + 48 * 256);
    int* rowptr = deg + N_NODES;                     // N_NODES+1
    int* rank   = rowptr + N_NODES + 1;              // N_EDGES
    int* srcs_sorted = rank + N_EDGES;               // N_EDGES
    int* bsum   = srcs_sorted + N_EDGES;             // NBLK
    unsigned short* aghi = (unsigned short*)(bsum + NBLK);   // agg planes (reused both layers)
    unsigned short* aglo = aghi + nd;
    unsigned short* h2hi = aglo + nd;                // h2 scratch (FINAL)
    unsigned short* h2lo = h2hi + nd;

    // ---- prep (casts/splits) + degree/rank histogram in one dispatch ----
    hipMemsetAsync(deg, 0, N_NODES * sizeof(int), stream);
    prep_deg_kernel<<<9551, 256, 0, stream>>>(dst, deg, rank, x, W1_l, W1_r, W2_l, W2_r, W_lin,
                                              xhi, xlo, W1hi, W1lo, W2hi, W2lo, WLhi, WLlo);

    // ---- CSR build ----
    scan_partial<<<NBLK, 256, 0, stream>>>(deg, bsum);
    scan_write<<<NBLK, 256, 0, stream>>>(deg, bsum, rowptr);
    bucket_kernel<<<(N_EDGES + 255) / 256, 256, 0, stream>>>(src, dst, rowptr, rank, srcs_sorted);

    const int lblk = (N_NODES + 31) / 32;            // 1563 blocks of 32 nodes

    // ---- layer 1 ----
    gather_mean<<<GATHER_BLOCKS, 256, 0, stream>>>(srcs_sorted, rowptr, xhi, aghi, aglo);
    gemm_layer<false><<<lblk, 256, 0, stream>>>(aghi, aglo, xhi, xlo,
                                                W1hi, W1lo, b1_l, h1hi, h1lo,
                                                nullptr, nullptr, nullptr, nullptr);
    // ---- layer 2 + classifier + log_softmax (h2 via global scratch) ----
    gather_mean<<<GATHER_BLOCKS, 256, 0, stream>>>(srcs_sorted, rowptr, h1hi, aghi, aglo);
    gemm_layer<true><<<lblk, 256, 0, stream>>>(aghi, aglo, h1hi, h1lo,
                                               W2hi, W2lo, b2_l, h2hi, h2lo,
                                               WLhi, WLlo, b_lin, out);
}